// Round 13
// baseline (94.738 us; speedup 1.0000x reference)
//
#include <hip/hip_runtime.h>
#include <math.h>

#define NREL  32
#define NENT  2048
#define NATTR 8
#define WIDTH 256
#define NK    (2 * NREL + NATTR)   // 72
#define CHUNKS_OUT 16              // partial rows per relation (128-row chunks)

typedef float f4 __attribute__((ext_vector_type(4)));

// ---------------------------------------------------------------------------
// Kernel A: one pass over database — the 94.7us R11 kernel (best known).
// Non-temporal db reads; fire-and-forget LDS row partials (rpart[64][129],
// (lane+row)%32 = exact 2-way banking); single deferred row-sum finish; 32KB
// column-combine buffer; 2 syncs total. A is NOT occupancy-limited (R7 5/CU
// == R10 2/CU) — it runs at ~5.85 TB/s, the NT streaming-read ceiling.
// ---------------------------------------------------------------------------
__global__ __launch_bounds__(256) void reduce_db_kernel(
    const float* __restrict__ db,
    float* __restrict__ qout,        // quantified region [72][2048]
    float* __restrict__ partial,     // [NREL*CHUNKS_OUT][2048]
    int rowsPerWave)                 // = 32 (runtime to forbid unrolling)
{
    const int bx   = blockIdx.x;
    const int r    = bx >> 4;              // / CHUNKS_OUT
    const int cOut = bx & (CHUNKS_OUT - 1);
    const int tid  = threadIdx.x;
    const int wave = tid >> 6;
    const int lane = tid & 63;

    __shared__ float rpart[64][129];                 // 33.0KB row partials
    __shared__ __align__(16) float csmem[4][NENT];   // 32KB column combine

    const size_t rowStride = NENT / 4;
    // wave owns 32 contiguous rows of this 128-row chunk
    const f4* base = reinterpret_cast<const f4*>(db)
                   + (size_t)r * NENT * rowStride
                   + (size_t)(cOut * 128 + wave * rowsPerWave) * rowStride
                   + lane;

    f4 acc[8];
#pragma unroll
    for (int k = 0; k < 8; ++k) acc[k] = (f4)0.f;

    for (int jj = 0; jj < rowsPerWave; jj += 2) {    // 16 iters, runtime bound
        const f4* rowA = base + (size_t)jj * rowStride;
        const f4* rowB = rowA + rowStride;
        float rsA = 0.f, rsB = 0.f;
        // 16 independent NON-TEMPORAL float4 loads; no cross-lane ops
#pragma unroll
        for (int k = 0; k < 8; ++k) {
            f4 v = __builtin_nontemporal_load(rowA + k * 64);
            acc[k] += v;
            rsA += (v.x + v.y) + (v.z + v.w);
        }
#pragma unroll
        for (int k = 0; k < 8; ++k) {
            f4 v = __builtin_nontemporal_load(rowB + k * 64);
            acc[k] += v;
            rsB += (v.x + v.y) + (v.z + v.w);
        }
        rpart[lane][wave * rowsPerWave + jj]     = rsA;
        rpart[lane][wave * rowsPerWave + jj + 1] = rsB;
    }
    __syncthreads();

    // single row-sum finish phase: thread t -> (row = t>>1, half = t&1)
    {
        const int row  = tid >> 1;       // 0..127
        const int half = tid & 1;
        float s = 0.f;
#pragma unroll
        for (int i = 0; i < 32; ++i) s += rpart[half * 32 + i][row];
        s += __shfl_xor(s, 1, 64);
        if (half == 0)
            qout[(size_t)(NREL + r) * NENT + cOut * 128 + row] =
                1.f - __expf(-s);
    }

    // combine the 4 waves' column partials (separate buffer, no extra sync)
#pragma unroll
    for (int k = 0; k < 8; ++k)
        *reinterpret_cast<f4*>(&csmem[wave][k * 256 + lane * 4]) = acc[k];
    __syncthreads();

    f4* part4 = reinterpret_cast<f4*>(partial) + (size_t)bx * rowStride;
    for (int g = tid; g < NENT / 4; g += 256) {
        f4 a0 = *reinterpret_cast<const f4*>(&csmem[0][g * 4]);
        f4 a1 = *reinterpret_cast<const f4*>(&csmem[1][g * 4]);
        f4 a2 = *reinterpret_cast<const f4*>(&csmem[2][g * 4]);
        f4 a3 = *reinterpret_cast<const f4*>(&csmem[3][g * 4]);
        part4[g] = (a0 + a1) + (a2 + a3);
    }
}

// ---------------------------------------------------------------------------
// Kernel T (tail, depends only on A) — 256 blocks. Block (wg 0..7, cg 0..31)
// = 32 w's x 64 cols. Stages qt[72][64]: rows 0..31 finalized from `partial`
// (16-chunk sums), rows 32..63 from A's qout, rows 64..71 from attrs. wg==0
// blocks write quant rows 0..31 / 64..71 for their col-slice. 32-w softmax
// per block via LDS. LDS ~29KB.
// ---------------------------------------------------------------------------
#define MM_BLOCKS  ((WIDTH / 32) * (NENT / 64))    // 256

__global__ __launch_bounds__(256) void tail_kernel(
    const float* __restrict__ partial,
    const float* __restrict__ attrs,
    const float* __restrict__ W,
    float* __restrict__ qout,
    float* __restrict__ out)
{
    const int b   = blockIdx.x;
    const int tid = threadIdx.x;

    __shared__ __align__(16) float qt[NK][68];   // 19.1KB (68 = 17*4)
    __shared__ float wsl[NK][33];                // 9.5KB W-slice / softmax
    const int wg = b >> 5;                 // 0..7
    const int cg = b & 31;                 // 0..31
    const int w0 = wg * 32;
    const int c0 = cg * 64;
    const int cq = c0 >> 2;                // first f4 col of slice

    const f4* part4  = reinterpret_cast<const f4*>(partial);
    const f4* qout4  = reinterpret_cast<const f4*>(qout);
    const f4* attrs4 = reinterpret_cast<const f4*>(attrs);
    f4*       qoutw4 = reinterpret_cast<f4*>(qout);

    // stage qt[72][64-col slice]  (4.5 iters of 256 threads)
    for (int i = tid; i < NK * 16; i += 256) {
        const int k  = i >> 4;
        const int cf = i & 15;
        f4 q;
        if (k < NREL) {
            f4 sum = (f4)0.f;
#pragma unroll
            for (int c = 0; c < CHUNKS_OUT; ++c)
                sum += part4[(size_t)(k * CHUNKS_OUT + c) * 512 + cq + cf];
            q.x = 1.f - __expf(-sum.x); q.y = 1.f - __expf(-sum.y);
            q.z = 1.f - __expf(-sum.z); q.w = 1.f - __expf(-sum.w);
            if (wg == 0) qoutw4[(size_t)k * 512 + cq + cf] = q;
        } else if (k < 2 * NREL) {
            q = qout4[(size_t)k * 512 + cq + cf];   // A already finalized
        } else {
            f4 v = attrs4[(size_t)(k - 2 * NREL) * 512 + cq + cf];
            q.x = 1.f - __expf(-2.f * v.x); q.y = 1.f - __expf(-2.f * v.y);
            q.z = 1.f - __expf(-2.f * v.z); q.w = 1.f - __expf(-2.f * v.w);
            if (wg == 0) qoutw4[(size_t)(k) * 512 + cq + cf] = q;
        }
        *reinterpret_cast<f4*>(&qt[k][cf * 4]) = q;
    }
    // stage W slice [72][32] (coalesced 32-wide rows)
    for (int i = tid; i < NK * 32; i += 256) {
        const int k  = i >> 5;
        const int wl = i & 31;
        wsl[k][wl] = W[k * WIDTH + w0 + wl];
    }
    __syncthreads();

    // softmax over k for this block's 32 w's (LDS-resident, conflict-free)
    if (tid < 32) {
        const int wl = tid;
        float m = wsl[0][wl];
#pragma unroll
        for (int k = 1; k < NK; ++k) m = fmaxf(m, wsl[k][wl]);
        float s = 0.f;
        float e[NK];
#pragma unroll
        for (int k = 0; k < NK; ++k) { e[k] = __expf(wsl[k][wl] - m); s += e[k]; }
        const float inv = 1.f / s;
#pragma unroll
        for (int k = 0; k < NK; ++k) wsl[k][wl] = e[k] * inv;
    }
    __syncthreads();

    // compute: thread = (wl = tid>>3, 8-col group cl = (tid&7)*8)
    const int wl = tid >> 3;
    const int cf = (tid & 7) * 2;          // f4 index within slice
    f4 a0 = (f4)0.f, a1 = (f4)0.f;
#pragma unroll 8
    for (int k = 0; k < NK; ++k) {
        const float s = wsl[k][wl];
        const f4* row = reinterpret_cast<const f4*>(&qt[k][0]);
        a0 += s * row[cf];
        a1 += s * row[cf + 1];
    }
    f4* o4 = reinterpret_cast<f4*>(out + (size_t)(w0 + wl) * NENT + c0) + cf;
    o4[0] = a0;
    o4[1] = a1;
}

extern "C" void kernel_launch(void* const* d_in, const int* in_sizes, int n_in,
                              void* d_out, int out_size, void* d_ws, size_t ws_size,
                              hipStream_t stream)
{
    const float* db    = (const float*)d_in[0];  // [32][2048][2048]
    const float* attrs = (const float*)d_in[1];  // [8][2048]
    const float* W     = (const float*)d_in[2];  // [72][256]

    float* out   = (float*)d_out;                    // [256][2048]
    float* quant = out + (size_t)WIDTH * NENT;       // [72][2048]

    float* partial = (float*)d_ws;                   // [512][2048] (4MB)

    reduce_db_kernel<<<NREL * CHUNKS_OUT, 256, 0, stream>>>(
        db, quant, partial, 32);
    tail_kernel<<<MM_BLOCKS, 256, 0, stream>>>(
        partial, attrs, W, quant, out);
}